// Round 4
// baseline (98.025 us; speedup 1.0000x reference)
//
#include <hip/hip_runtime.h>
#include <hip/hip_bf16.h>

typedef __bf16 bf16x8 __attribute__((ext_vector_type(8)));
typedef float f32x4 __attribute__((ext_vector_type(4)));

#define NB 32
#define CIN 512
#define COUT 128
#define NP 3136   // 56*56
#define WIMG 56

__device__ __forceinline__ unsigned fenc(float f) {
    unsigned u = __float_as_uint(f);
    return (u & 0x80000000u) ? ~u : (u | 0x80000000u);
}
__device__ __forceinline__ float fdec(unsigned e) {
    unsigned u = (e & 0x80000000u) ? (e ^ 0x80000000u) : ~e;
    return __uint_as_float(u);
}
__device__ __forceinline__ float bflo(unsigned u) { return __uint_as_float(u << 16); }
__device__ __forceinline__ float bfhi(unsigned u) { return __uint_as_float(u & 0xffff0000u); }

// Relaxed barrier: LDS-visibility only, no vmcnt drain (keep prefetch in flight).
__device__ __forceinline__ void lds_barrier() {
    asm volatile("s_waitcnt lgkmcnt(0)" ::: "memory");
    __builtin_amdgcn_s_barrier();
    __builtin_amdgcn_sched_barrier(0);
}

// ---------------------------------------------------------------------------
// Kernel 0: W f32 -> bf16, plus zero-init of sumh/mxenc (replaces memset node).
// ---------------------------------------------------------------------------
__global__ __launch_bounds__(256) void k_wcvt(const float* __restrict__ wp,
                                              ushort* __restrict__ wb,
                                              unsigned* __restrict__ zero8k)
{
    int i = blockIdx.x * 256 + threadIdx.x;   // 16384 threads, 4 elems each
    if (i < 2 * NB * COUT) zero8k[i] = 0u;
    float4 f = *(const float4*)(wp + i * 4);
    ushort4 u;
    __bf16 b0 = (__bf16)f.x, b1 = (__bf16)f.y, b2 = (__bf16)f.z, b3 = (__bf16)f.w;
    u.x = *(ushort*)&b0; u.y = *(ushort*)&b1; u.z = *(ushort*)&b2; u.w = *(ushort*)&b3;
    *(ushort4*)(wb + i * 4) = u;
}

// ---------------------------------------------------------------------------
// Kernel 1: GEMM (W[128,512] @ X_b[512,3136]) + BN + SiLU, store h (bf16),
// accumulate per-(b,o) spatial sum and max.
// 512 threads (8 waves); wave w owns rows o=w*16..+15, A-fragments (whole K)
// in registers. X tile [64p][64k] bf16, double-buffered LDS, XOR-swizzled,
// distance-2 register prefetch, relaxed barriers (no vmcnt drain).
// ---------------------------------------------------------------------------
__global__ __launch_bounds__(512, 4) void k_main(
    const float* __restrict__ x, const ushort* __restrict__ wb,
    const float* __restrict__ bn_g, const float* __restrict__ bn_b,
    const float* __restrict__ bn_m, const float* __restrict__ bn_v,
    ushort* __restrict__ hout, float* __restrict__ sumh, unsigned* __restrict__ mxenc)
{
    __shared__ __align__(16) ushort Xs[2][64 * 64];  // 8KB each
    __shared__ float bnss[256];

    const int t    = threadIdx.x;
    const int b    = blockIdx.x / 49;
    const int p0   = (blockIdx.x % 49) * 64;
    const int lane = t & 63;
    const int l15  = lane & 15;
    const int lg   = lane >> 4;     // 0..3
    const int w    = t >> 6;        // wave 0..7

    if (t < COUT) {
        float sc = bn_g[t] * rsqrtf(bn_v[t] + 1e-5f);
        bnss[t]        = sc;
        bnss[t + COUT] = bn_b[t] - bn_m[t] * sc;
    }

    // ---- A-fragments (W) for the whole K dimension: 16 x bf16x8 = 64 VGPR
    const ushort* wrow = wb + (w * 16 + l15) * CIN + lg * 8;
    bf16x8 af[16];
#pragma unroll
    for (int ks = 0; ks < 16; ++ks)
        af[ks] = *(const bf16x8*)(wrow + ks * 32);

    // ---- staging geometry: thread t stages row p=t&63, k-octet kg=w
    const int pr = t & 63;
    const int kg = w;
    const float* xb = x + ((size_t)b * CIN) * NP + p0 + pr;
    const int wbyte = pr * 128 + ((kg * 16) ^ ((pr & 7) << 4));

    f32x4 acc[4];
#pragma unroll
    for (int nf = 0; nf < 4; ++nf) acc[nf] = (f32x4){0.f, 0.f, 0.f, 0.f};

    float ld[2][8];

    // prologue: issue tiles 0 and 1; write tile 0 into buf 0
#pragma unroll
    for (int j = 0; j < 8; ++j) ld[0][j] = xb[(kg * 8 + j) * NP];
#pragma unroll
    for (int j = 0; j < 8; ++j) ld[1][j] = xb[(64 + kg * 8 + j) * NP];
    {
        bf16x8 v8;
#pragma unroll
        for (int j = 0; j < 8; ++j) v8[j] = (__bf16)ld[0][j];
        *(bf16x8*)((char*)Xs[0] + wbyte) = v8;
    }

#pragma unroll
    for (int kc = 0; kc < 8; ++kc) {
        lds_barrier();
        // issue tile kc+2 into the reg set freed by tile kc (distance-2 prefetch)
        if (kc < 6) {
#pragma unroll
            for (int j = 0; j < 8; ++j)
                ld[kc & 1][j] = xb[((kc + 2) * 64 + kg * 8 + j) * NP];
        }
        // compute current tile from Xs[kc&1]
#pragma unroll
        for (int ks = 0; ks < 2; ++ks) {
#pragma unroll
            for (int nf = 0; nf < 4; ++nf) {
                int row  = nf * 16 + l15;
                int byte = row * 128 + ((ks * 64 + lg * 16) ^ ((row & 7) << 4));
                bf16x8 bfr = *(const bf16x8*)((const char*)Xs[kc & 1] + byte);
                acc[nf] = __builtin_amdgcn_mfma_f32_16x16x32_bf16(
                    af[kc * 2 + ks], bfr, acc[nf], 0, 0, 0);
            }
        }
        // write-late: cvt + ds_write tile kc+1 (issued one iteration ago)
        if (kc < 7) {
            bf16x8 v8;
#pragma unroll
            for (int j = 0; j < 8; ++j) v8[j] = (__bf16)ld[(kc + 1) & 1][j];
            *(bf16x8*)((char*)Xs[(kc + 1) & 1] + wbyte) = v8;
        }
    }

    // ---- epilogue: BN + SiLU, store bf16 h, per-(b,o) sum/max
#pragma unroll
    for (int reg = 0; reg < 4; ++reg) {
        int o = w * 16 + lg * 4 + reg;
        float sc = bnss[o], sh = bnss[o + COUT];
        float s_ = 0.f, m_ = -1e30f;
#pragma unroll
        for (int nf = 0; nf < 4; ++nf) {
            float d    = acc[nf][reg];
            float hval = d * sc + sh;
            hval       = hval / (1.f + __expf(-hval));
            s_ += hval;
            m_ = fmaxf(m_, hval);
            int p      = p0 + nf * 16 + l15;
            __bf16 hb  = (__bf16)hval;
            hout[((size_t)b * COUT + o) * NP + p] = *(ushort*)&hb;
        }
#pragma unroll
        for (int d = 1; d < 16; d <<= 1) {
            s_ += __shfl_xor(s_, d, 64);
            m_ = fmaxf(m_, __shfl_xor(m_, d, 64));
        }
        if (l15 == 0) {
            atomicAdd(&sumh[b * COUT + o], s_);
            atomicMax(&mxenc[b * COUT + o], fenc(m_));
        }
    }
}

// ---------------------------------------------------------------------------
// Kernel 2: channel attention MLP -> ca[32,128]
// ---------------------------------------------------------------------------
__global__ void k_ca(const float* __restrict__ sumh, const unsigned* __restrict__ mxenc,
                     const float* __restrict__ w1, const float* __restrict__ w2,
                     float* __restrict__ ca)
{
    int b = blockIdx.x, t = threadIdx.x;   // 128 threads
    __shared__ float avg[128], mx[128], r1[16];
    avg[t] = sumh[b * COUT + t] * (1.f / (float)NP);
    mx[t]  = fdec(mxenc[b * COUT + t]);
    __syncthreads();
    if (t < 16) {
        int r = t & 7;
        const float* p = (t < 8) ? avg : mx;
        float s = 0.f;
        for (int c = 0; c < 128; ++c) s += w1[r * 128 + c] * p[c];
        r1[t] = fmaxf(s, 0.f);
    }
    __syncthreads();
    float s = 0.f;
#pragma unroll
    for (int r = 0; r < 8; ++r) s += w2[t * 8 + r] * (r1[r] + r1[r + 8]);
    ca[b * COUT + t] = 1.f / (1.f + __expf(-s));
}

// ---------------------------------------------------------------------------
// Kernel 3: spatial stats of (h * ca): per-position channel sum & max,
// channel-split 4 ways. sbuf[z][b][{sum,max}][p]
// ---------------------------------------------------------------------------
__global__ __launch_bounds__(256) void k_sstat(const ushort* __restrict__ h,
                                               const float* __restrict__ ca,
                                               float* __restrict__ sbuf)
{
    int b = blockIdx.y, z = blockIdx.z;
    int pp = blockIdx.x * 256 + threadIdx.x;  // pair index
    __shared__ float cas[32];
    if (threadIdx.x < 32) cas[threadIdx.x] = ca[b * COUT + z * 32 + threadIdx.x];
    __syncthreads();
    if (pp >= NP / 2) return;
    int p = pp * 2;
    const ushort* hb = h + ((size_t)b * COUT + z * 32) * NP + p;
    float s0 = 0.f, s1 = 0.f, m0 = -1e30f, m1 = -1e30f;
#pragma unroll 4
    for (int c = 0; c < 32; ++c) {
        unsigned u = *(const unsigned*)(hb + (size_t)c * NP);
        float cv = cas[c];
        float v0 = bflo(u) * cv;
        float v1 = bfhi(u) * cv;
        s0 += v0; s1 += v1;
        m0 = fmaxf(m0, v0); m1 = fmaxf(m1, v1);
    }
    float* sb = sbuf + ((size_t)(z * NB + b) * 2) * NP;
    sb[p] = s0; sb[p + 1] = s1;
    sb[NP + p] = m0; sb[NP + p + 1] = m1;
}

// ---------------------------------------------------------------------------
// Kernel 4: combine quarters, 7x7 conv (pad 3) + sigmoid -> sigsa[32,3136]
// Row-band parallel: grid (4 bands x NB), each band = 14 rows + 3-row halo.
// ---------------------------------------------------------------------------
__global__ __launch_bounds__(256) void k_conv(const float* __restrict__ sbuf,
                                              const float* __restrict__ saw,
                                              float* __restrict__ sigsa)
{
    int band = blockIdx.x, b = blockIdx.y;
    int y0 = band * 14;
    int t = threadIdx.x;
    __shared__ float s[2][20 * WIMG];
    __shared__ float w[98];
    if (t < 98) w[t] = saw[t];
    for (int i = t; i < 20 * WIMG; i += 256) {
        int yy = y0 - 3 + i / WIMG;
        float vs = 0.f, vm = 0.f;
        if (yy >= 0 && yy < WIMG) {
            int p = yy * WIMG + (i % WIMG);
            float ssum = 0.f, smax = -1e30f;
#pragma unroll
            for (int z = 0; z < 4; ++z) {
                const float* sb = sbuf + ((size_t)(z * NB + b) * 2) * NP;
                ssum += sb[p];
                smax = fmaxf(smax, sb[NP + p]);
            }
            vs = ssum * (1.f / (float)COUT);
            vm = smax;
        }
        s[0][i] = vs;
        s[1][i] = vm;
    }
    __syncthreads();
    for (int i = t; i < 14 * WIMG; i += 256) {
        int ly = i / WIMG, px = i % WIMG;
        float a = 0.f;
#pragma unroll
        for (int ch = 0; ch < 2; ++ch) {
#pragma unroll
            for (int dy = 0; dy < 7; ++dy) {
                int li = (ly + dy) * WIMG;
                for (int dx = 0; dx < 7; ++dx) {
                    int xx = px + dx - 3;
                    if (xx < 0 || xx >= WIMG) continue;
                    a += s[ch][li + xx] * w[ch * 49 + dy * 7 + dx];
                }
            }
        }
        sigsa[b * NP + (y0 + ly) * WIMG + px] = 1.f / (1.f + __expf(-a));
    }
}

// ---------------------------------------------------------------------------
// Kernel 5: t = sum_p h * sigsa ; y = (sum_h + ca*t)/P.  One block per (b,o).
// ---------------------------------------------------------------------------
__global__ __launch_bounds__(256) void k_wsum(const ushort* __restrict__ h,
                                              const float* __restrict__ sigsa,
                                              const float* __restrict__ sumh,
                                              const float* __restrict__ ca,
                                              float* __restrict__ y)
{
    int bo = blockIdx.x;          // b*128+o
    int b = bo >> 7;
    int t = threadIdx.x;
    const ushort* hr = h + (size_t)bo * NP;
    const float* sg  = sigsa + (size_t)b * NP;
    float s = 0.f;
#pragma unroll
    for (int i = 0; i < 3; ++i) {
        int q = (i * 256 + t) * 4;
        uint2 u = *(const uint2*)(hr + q);
        float4 g = *(const float4*)(sg + q);
        s += bflo(u.x) * g.x + bfhi(u.x) * g.y + bflo(u.y) * g.z + bfhi(u.y) * g.w;
    }
    if (t < 16) {
        int q = (768 + t) * 4;
        uint2 u = *(const uint2*)(hr + q);
        float4 g = *(const float4*)(sg + q);
        s += bflo(u.x) * g.x + bfhi(u.x) * g.y + bflo(u.y) * g.z + bfhi(u.y) * g.w;
    }
#pragma unroll
    for (int d = 1; d < 64; d <<= 1) s += __shfl_xor(s, d, 64);
    __shared__ float part[4];
    if ((t & 63) == 0) part[t >> 6] = s;
    __syncthreads();
    if (t == 0) {
        float tt = part[0] + part[1] + part[2] + part[3];
        y[bo] = (sumh[bo] + ca[bo] * tt) * (1.f / (float)NP);
    }
}

// ---------------------------------------------------------------------------
// Kernel 6: LayerNorm over channels -> out[32,128]
// ---------------------------------------------------------------------------
__global__ void k_ln(const float* __restrict__ y, const float* __restrict__ g,
                     const float* __restrict__ bta, float* __restrict__ out)
{
    int b = blockIdx.x, t = threadIdx.x;  // 128 threads
    __shared__ float pr[2], pr2[2];
    float v = y[b * COUT + t];
    float s = v;
#pragma unroll
    for (int d = 1; d < 64; d <<= 1) s += __shfl_xor(s, d, 64);
    if ((t & 63) == 0) pr[t >> 6] = s;
    __syncthreads();
    float mu = (pr[0] + pr[1]) * (1.f / (float)COUT);
    float dv = v - mu;
    float q = dv * dv;
#pragma unroll
    for (int d = 1; d < 64; d <<= 1) q += __shfl_xor(q, d, 64);
    if ((t & 63) == 0) pr2[t >> 6] = q;
    __syncthreads();
    float var = (pr2[0] + pr2[1]) * (1.f / (float)COUT);
    out[b * COUT + t] = dv * rsqrtf(var + 1e-5f) * g[t] + bta[t];
}

// ---------------------------------------------------------------------------
extern "C" void kernel_launch(void* const* d_in, const int* in_sizes, int n_in,
                              void* d_out, int out_size, void* d_ws, size_t ws_size,
                              hipStream_t stream)
{
    const float* x     = (const float*)d_in[0];
    const float* wp    = (const float*)d_in[1];
    const float* bn_g  = (const float*)d_in[2];
    const float* bn_b  = (const float*)d_in[3];
    const float* bn_m  = (const float*)d_in[4];
    const float* bn_v  = (const float*)d_in[5];
    const float* ca_w1 = (const float*)d_in[6];
    const float* ca_w2 = (const float*)d_in[7];
    const float* sa_w  = (const float*)d_in[8];
    const float* ln_g  = (const float*)d_in[9];
    const float* ln_b  = (const float*)d_in[10];
    float* out = (float*)d_out;

    char* ws = (char*)d_ws;
    size_t off = 0;
    ushort*   hbuf  = (ushort*)(ws + off);   off += (size_t)NB * COUT * NP * 2;  // 25,690,112
    float*    sumh  = (float*)(ws + off);    off += NB * COUT * 4;               // 16 KB
    unsigned* mxenc = (unsigned*)(ws + off); off += NB * COUT * 4;               // 16 KB
    float*    ca    = (float*)(ws + off);    off += NB * COUT * 4;               // 16 KB
    float*    sbuf  = (float*)(ws + off);    off += (size_t)4 * NB * 2 * NP * 4; // 3.2 MB
    float*    sigsa = (float*)(ws + off);    off += (size_t)NB * NP * 4;         // 0.4 MB
    float*    ybuf  = (float*)(ws + off);    off += NB * COUT * 4;
    ushort*   wb16  = (ushort*)(ws + off);   off += (size_t)COUT * CIN * 2;      // 128 KB

    k_wcvt<<<64, 256, 0, stream>>>(wp, wb16, (unsigned*)sumh);
    k_main<<<NB * 49, 512, 0, stream>>>(x, wb16, bn_g, bn_b, bn_m, bn_v, hbuf, sumh, mxenc);
    k_ca<<<NB, 128, 0, stream>>>(sumh, mxenc, ca_w1, ca_w2, ca);
    k_sstat<<<dim3(7, NB, 4), 256, 0, stream>>>(hbuf, ca, sbuf);
    k_conv<<<dim3(4, NB), 256, 0, stream>>>(sbuf, sa_w, sigsa);
    k_wsum<<<NB * COUT, 256, 0, stream>>>(hbuf, sigsa, sumh, ca, ybuf);
    k_ln<<<NB, 128, 0, stream>>>(ybuf, ln_g, ln_b, out);
}

// Round 5
// 89.514 us; speedup vs baseline: 1.0951x; 1.0951x over previous
//
#include <hip/hip_runtime.h>
#include <hip/hip_bf16.h>

typedef __bf16 bf16x8 __attribute__((ext_vector_type(8)));
typedef float f32x4 __attribute__((ext_vector_type(4)));

#define NB 32
#define CIN 512
#define COUT 128
#define NP 3136   // 56*56
#define WIMG 56

__device__ __forceinline__ unsigned fenc(float f) {
    unsigned u = __float_as_uint(f);
    return (u & 0x80000000u) ? ~u : (u | 0x80000000u);
}
__device__ __forceinline__ float fdec(unsigned e) {
    unsigned u = (e & 0x80000000u) ? (e ^ 0x80000000u) : ~e;
    return __uint_as_float(u);
}
__device__ __forceinline__ float bflo(unsigned u) { return __uint_as_float(u << 16); }
__device__ __forceinline__ float bfhi(unsigned u) { return __uint_as_float(u & 0xffff0000u); }

// Relaxed barrier: LDS-visibility only, no vmcnt drain (keep prefetch in flight).
__device__ __forceinline__ void lds_barrier() {
    asm volatile("s_waitcnt lgkmcnt(0)" ::: "memory");
    __builtin_amdgcn_s_barrier();
    __builtin_amdgcn_sched_barrier(0);
}

// ---------------------------------------------------------------------------
// Kernel 0: W f32 -> bf16, plus zero-init of sumh/mxenc (replaces memset node).
// ---------------------------------------------------------------------------
__global__ __launch_bounds__(256) void k_wcvt(const float* __restrict__ wp,
                                              ushort* __restrict__ wb,
                                              unsigned* __restrict__ zero8k)
{
    int i = blockIdx.x * 256 + threadIdx.x;   // 16384 threads, 4 elems each
    if (i < 2 * NB * COUT) zero8k[i] = 0u;
    float4 f = *(const float4*)(wp + i * 4);
    ushort4 u;
    __bf16 b0 = (__bf16)f.x, b1 = (__bf16)f.y, b2 = (__bf16)f.z, b3 = (__bf16)f.w;
    u.x = *(ushort*)&b0; u.y = *(ushort*)&b1; u.z = *(ushort*)&b2; u.w = *(ushort*)&b3;
    *(ushort4*)(wb + i * 4) = u;
}

// ---------------------------------------------------------------------------
// Kernel 1: GEMM (W[128,512] @ X_b[512,3136]) + BN + SiLU, store h (bf16),
// accumulate per-(b,o) spatial sum and max.
// 512 threads (8 waves); wave w owns rows o=w*16..+15, A-fragments (whole K)
// in registers. X tile [64p][64k] bf16, double-buffered LDS, XOR-swizzled,
// distance-2 register prefetch. XCD-aware block swizzle: each XCD owns
// 196 consecutive work-items = 4 whole images (all 49 p-slices co-resident
// on one XCD L2 -> strided 256B chunks merge into full-row streams).
// ---------------------------------------------------------------------------
__global__ __launch_bounds__(512, 4) void k_main(
    const float* __restrict__ x, const ushort* __restrict__ wb,
    const float* __restrict__ bn_g, const float* __restrict__ bn_b,
    const float* __restrict__ bn_m, const float* __restrict__ bn_v,
    ushort* __restrict__ hout, float* __restrict__ sumh, unsigned* __restrict__ mxenc)
{
    __shared__ __align__(16) ushort Xs[2][64 * 64];  // 8KB each
    __shared__ float bnss[256];

    const int bid  = blockIdx.x;                    // 0..1567, 1568 % 8 == 0
    const int swz  = (bid & 7) * 196 + (bid >> 3);  // bijective XCD swizzle
    const int t    = threadIdx.x;
    const int b    = swz / 49;
    const int p0   = (swz % 49) * 64;
    const int lane = t & 63;
    const int l15  = lane & 15;
    const int lg   = lane >> 4;     // 0..3
    const int w    = t >> 6;        // wave 0..7

    if (t < COUT) {
        float sc = bn_g[t] * rsqrtf(bn_v[t] + 1e-5f);
        bnss[t]        = sc;
        bnss[t + COUT] = bn_b[t] - bn_m[t] * sc;
    }

    // ---- A-fragments (W) for the whole K dimension: 16 x bf16x8 = 64 VGPR
    const ushort* wrow = wb + (w * 16 + l15) * CIN + lg * 8;
    bf16x8 af[16];
#pragma unroll
    for (int ks = 0; ks < 16; ++ks)
        af[ks] = *(const bf16x8*)(wrow + ks * 32);

    // ---- staging geometry: thread t stages row p=t&63, k-octet kg=w
    const int pr = t & 63;
    const int kg = w;
    const float* xb = x + ((size_t)b * CIN) * NP + p0 + pr;
    const int wbyte = pr * 128 + ((kg * 16) ^ ((pr & 7) << 4));

    f32x4 acc[4];
#pragma unroll
    for (int nf = 0; nf < 4; ++nf) acc[nf] = (f32x4){0.f, 0.f, 0.f, 0.f};

    float ld[2][8];

    // prologue: issue tiles 0 and 1; write tile 0 into buf 0
#pragma unroll
    for (int j = 0; j < 8; ++j) ld[0][j] = xb[(kg * 8 + j) * NP];
#pragma unroll
    for (int j = 0; j < 8; ++j) ld[1][j] = xb[(64 + kg * 8 + j) * NP];
    {
        bf16x8 v8;
#pragma unroll
        for (int j = 0; j < 8; ++j) v8[j] = (__bf16)ld[0][j];
        *(bf16x8*)((char*)Xs[0] + wbyte) = v8;
    }

#pragma unroll
    for (int kc = 0; kc < 8; ++kc) {
        lds_barrier();
        // issue tile kc+2 into the reg set freed by tile kc (distance-2 prefetch)
        if (kc < 6) {
#pragma unroll
            for (int j = 0; j < 8; ++j)
                ld[kc & 1][j] = xb[((kc + 2) * 64 + kg * 8 + j) * NP];
        }
        // compute current tile from Xs[kc&1]
#pragma unroll
        for (int ks = 0; ks < 2; ++ks) {
#pragma unroll
            for (int nf = 0; nf < 4; ++nf) {
                int row  = nf * 16 + l15;
                int byte = row * 128 + ((ks * 64 + lg * 16) ^ ((row & 7) << 4));
                bf16x8 bfr = *(const bf16x8*)((const char*)Xs[kc & 1] + byte);
                acc[nf] = __builtin_amdgcn_mfma_f32_16x16x32_bf16(
                    af[kc * 2 + ks], bfr, acc[nf], 0, 0, 0);
            }
        }
        // write-late: cvt + ds_write tile kc+1 (issued one iteration ago)
        if (kc < 7) {
            bf16x8 v8;
#pragma unroll
            for (int j = 0; j < 8; ++j) v8[j] = (__bf16)ld[(kc + 1) & 1][j];
            *(bf16x8*)((char*)Xs[(kc + 1) & 1] + wbyte) = v8;
        }
    }

    // ---- epilogue: BN + SiLU, store bf16 h, per-(b,o) sum/max
#pragma unroll
    for (int reg = 0; reg < 4; ++reg) {
        int o = w * 16 + lg * 4 + reg;
        float sc = bnss[o], sh = bnss[o + COUT];
        float s_ = 0.f, m_ = -1e30f;
#pragma unroll
        for (int nf = 0; nf < 4; ++nf) {
            float d    = acc[nf][reg];
            float hval = d * sc + sh;
            hval       = hval / (1.f + __expf(-hval));
            s_ += hval;
            m_ = fmaxf(m_, hval);
            int p      = p0 + nf * 16 + l15;
            __bf16 hb  = (__bf16)hval;
            hout[((size_t)b * COUT + o) * NP + p] = *(ushort*)&hb;
        }
#pragma unroll
        for (int d = 1; d < 16; d <<= 1) {
            s_ += __shfl_xor(s_, d, 64);
            m_ = fmaxf(m_, __shfl_xor(m_, d, 64));
        }
        if (l15 == 0) {
            atomicAdd(&sumh[b * COUT + o], s_);
            atomicMax(&mxenc[b * COUT + o], fenc(m_));
        }
    }
}

// ---------------------------------------------------------------------------
// Kernel 2: channel attention MLP -> ca[32,128]
// ---------------------------------------------------------------------------
__global__ void k_ca(const float* __restrict__ sumh, const unsigned* __restrict__ mxenc,
                     const float* __restrict__ w1, const float* __restrict__ w2,
                     float* __restrict__ ca)
{
    int b = blockIdx.x, t = threadIdx.x;   // 128 threads
    __shared__ float avg[128], mx[128], r1[16];
    avg[t] = sumh[b * COUT + t] * (1.f / (float)NP);
    mx[t]  = fdec(mxenc[b * COUT + t]);
    __syncthreads();
    if (t < 16) {
        int r = t & 7;
        const float* p = (t < 8) ? avg : mx;
        float s = 0.f;
        for (int c = 0; c < 128; ++c) s += w1[r * 128 + c] * p[c];
        r1[t] = fmaxf(s, 0.f);
    }
    __syncthreads();
    float s = 0.f;
#pragma unroll
    for (int r = 0; r < 8; ++r) s += w2[t * 8 + r] * (r1[r] + r1[r + 8]);
    ca[b * COUT + t] = 1.f / (1.f + __expf(-s));
}

// ---------------------------------------------------------------------------
// Kernel 3: spatial stats of (h * ca): per-position channel sum & max,
// channel-split 4 ways. sbuf[z][b][{sum,max}][p]
// ---------------------------------------------------------------------------
__global__ __launch_bounds__(256) void k_sstat(const ushort* __restrict__ h,
                                               const float* __restrict__ ca,
                                               float* __restrict__ sbuf)
{
    int b = blockIdx.y, z = blockIdx.z;
    int pp = blockIdx.x * 256 + threadIdx.x;  // pair index
    __shared__ float cas[32];
    if (threadIdx.x < 32) cas[threadIdx.x] = ca[b * COUT + z * 32 + threadIdx.x];
    __syncthreads();
    if (pp >= NP / 2) return;
    int p = pp * 2;
    const ushort* hb = h + ((size_t)b * COUT + z * 32) * NP + p;
    float s0 = 0.f, s1 = 0.f, m0 = -1e30f, m1 = -1e30f;
#pragma unroll 4
    for (int c = 0; c < 32; ++c) {
        unsigned u = *(const unsigned*)(hb + (size_t)c * NP);
        float cv = cas[c];
        float v0 = bflo(u) * cv;
        float v1 = bfhi(u) * cv;
        s0 += v0; s1 += v1;
        m0 = fmaxf(m0, v0); m1 = fmaxf(m1, v1);
    }
    float* sb = sbuf + ((size_t)(z * NB + b) * 2) * NP;
    sb[p] = s0; sb[p + 1] = s1;
    sb[NP + p] = m0; sb[NP + p + 1] = m1;
}

// ---------------------------------------------------------------------------
// Kernel 4: combine quarters, 7x7 conv (pad 3) + sigmoid -> sigsa[32,3136]
// Row-band parallel: grid (8 bands x NB), each band = 7 rows + 3-row halo.
// ---------------------------------------------------------------------------
__global__ __launch_bounds__(256) void k_conv(const float* __restrict__ sbuf,
                                              const float* __restrict__ saw,
                                              float* __restrict__ sigsa)
{
    int band = blockIdx.x, b = blockIdx.y;
    int y0 = band * 7;
    int t = threadIdx.x;
    __shared__ float s[2][13 * WIMG];
    __shared__ float w[98];
    if (t < 98) w[t] = saw[t];
    for (int i = t; i < 13 * WIMG; i += 256) {
        int yy = y0 - 3 + i / WIMG;
        float vs = 0.f, vm = 0.f;
        if (yy >= 0 && yy < WIMG) {
            int p = yy * WIMG + (i % WIMG);
            float ssum = 0.f, smax = -1e30f;
#pragma unroll
            for (int z = 0; z < 4; ++z) {
                const float* sb = sbuf + ((size_t)(z * NB + b) * 2) * NP;
                ssum += sb[p];
                smax = fmaxf(smax, sb[NP + p]);
            }
            vs = ssum * (1.f / (float)COUT);
            vm = smax;
        }
        s[0][i] = vs;
        s[1][i] = vm;
    }
    __syncthreads();
    for (int i = t; i < 7 * WIMG; i += 256) {
        int ly = i / WIMG, px = i % WIMG;
        float a = 0.f;
#pragma unroll
        for (int ch = 0; ch < 2; ++ch) {
#pragma unroll
            for (int dy = 0; dy < 7; ++dy) {
                int li = (ly + dy) * WIMG;
                for (int dx = 0; dx < 7; ++dx) {
                    int xx = px + dx - 3;
                    if (xx < 0 || xx >= WIMG) continue;
                    a += s[ch][li + xx] * w[ch * 49 + dy * 7 + dx];
                }
            }
        }
        sigsa[b * NP + (y0 + ly) * WIMG + px] = 1.f / (1.f + __expf(-a));
    }
}

// ---------------------------------------------------------------------------
// Kernel 5: t = sum_p h * sigsa ; y = (sum_h + ca*t)/P.  One block per (b,o).
// ---------------------------------------------------------------------------
__global__ __launch_bounds__(256) void k_wsum(const ushort* __restrict__ h,
                                              const float* __restrict__ sigsa,
                                              const float* __restrict__ sumh,
                                              const float* __restrict__ ca,
                                              float* __restrict__ y)
{
    int bo = blockIdx.x;          // b*128+o
    int b = bo >> 7;
    int t = threadIdx.x;
    const ushort* hr = h + (size_t)bo * NP;
    const float* sg  = sigsa + (size_t)b * NP;
    float s = 0.f;
#pragma unroll
    for (int i = 0; i < 3; ++i) {
        int q = (i * 256 + t) * 4;
        uint2 u = *(const uint2*)(hr + q);
        float4 g = *(const float4*)(sg + q);
        s += bflo(u.x) * g.x + bfhi(u.x) * g.y + bflo(u.y) * g.z + bfhi(u.y) * g.w;
    }
    if (t < 16) {
        int q = (768 + t) * 4;
        uint2 u = *(const uint2*)(hr + q);
        float4 g = *(const float4*)(sg + q);
        s += bflo(u.x) * g.x + bfhi(u.x) * g.y + bflo(u.y) * g.z + bfhi(u.y) * g.w;
    }
#pragma unroll
    for (int d = 1; d < 64; d <<= 1) s += __shfl_xor(s, d, 64);
    __shared__ float part[4];
    if ((t & 63) == 0) part[t >> 6] = s;
    __syncthreads();
    if (t == 0) {
        float tt = part[0] + part[1] + part[2] + part[3];
        y[bo] = (sumh[bo] + ca[bo] * tt) * (1.f / (float)NP);
    }
}

// ---------------------------------------------------------------------------
// Kernel 6: LayerNorm over channels -> out[32,128]
// ---------------------------------------------------------------------------
__global__ void k_ln(const float* __restrict__ y, const float* __restrict__ g,
                     const float* __restrict__ bta, float* __restrict__ out)
{
    int b = blockIdx.x, t = threadIdx.x;  // 128 threads
    __shared__ float pr[2], pr2[2];
    float v = y[b * COUT + t];
    float s = v;
#pragma unroll
    for (int d = 1; d < 64; d <<= 1) s += __shfl_xor(s, d, 64);
    if ((t & 63) == 0) pr[t >> 6] = s;
    __syncthreads();
    float mu = (pr[0] + pr[1]) * (1.f / (float)COUT);
    float dv = v - mu;
    float q = dv * dv;
#pragma unroll
    for (int d = 1; d < 64; d <<= 1) q += __shfl_xor(q, d, 64);
    if ((t & 63) == 0) pr2[t >> 6] = q;
    __syncthreads();
    float var = (pr2[0] + pr2[1]) * (1.f / (float)COUT);
    out[b * COUT + t] = dv * rsqrtf(var + 1e-5f) * g[t] + bta[t];
}

// ---------------------------------------------------------------------------
extern "C" void kernel_launch(void* const* d_in, const int* in_sizes, int n_in,
                              void* d_out, int out_size, void* d_ws, size_t ws_size,
                              hipStream_t stream)
{
    const float* x     = (const float*)d_in[0];
    const float* wp    = (const float*)d_in[1];
    const float* bn_g  = (const float*)d_in[2];
    const float* bn_b  = (const float*)d_in[3];
    const float* bn_m  = (const float*)d_in[4];
    const float* bn_v  = (const float*)d_in[5];
    const float* ca_w1 = (const float*)d_in[6];
    const float* ca_w2 = (const float*)d_in[7];
    const float* sa_w  = (const float*)d_in[8];
    const float* ln_g  = (const float*)d_in[9];
    const float* ln_b  = (const float*)d_in[10];
    float* out = (float*)d_out;

    char* ws = (char*)d_ws;
    size_t off = 0;
    ushort*   hbuf  = (ushort*)(ws + off);   off += (size_t)NB * COUT * NP * 2;  // 25,690,112
    float*    sumh  = (float*)(ws + off);    off += NB * COUT * 4;               // 16 KB
    unsigned* mxenc = (unsigned*)(ws + off); off += NB * COUT * 4;               // 16 KB
    float*    ca    = (float*)(ws + off);    off += NB * COUT * 4;               // 16 KB
    float*    sbuf  = (float*)(ws + off);    off += (size_t)4 * NB * 2 * NP * 4; // 3.2 MB
    float*    sigsa = (float*)(ws + off);    off += (size_t)NB * NP * 4;         // 0.4 MB
    float*    ybuf  = (float*)(ws + off);    off += NB * COUT * 4;
    ushort*   wb16  = (ushort*)(ws + off);   off += (size_t)COUT * CIN * 2;      // 128 KB

    k_wcvt<<<64, 256, 0, stream>>>(wp, wb16, (unsigned*)sumh);
    k_main<<<NB * 49, 512, 0, stream>>>(x, wb16, bn_g, bn_b, bn_m, bn_v, hbuf, sumh, mxenc);
    k_ca<<<NB, 128, 0, stream>>>(sumh, mxenc, ca_w1, ca_w2, ca);
    k_sstat<<<dim3(7, NB, 4), 256, 0, stream>>>(hbuf, ca, sbuf);
    k_conv<<<dim3(8, NB), 256, 0, stream>>>(sbuf, sa_w, sigsa);
    k_wsum<<<NB * COUT, 256, 0, stream>>>(hbuf, sigsa, sumh, ca, ybuf);
    k_ln<<<NB, 128, 0, stream>>>(ybuf, ln_g, ln_b, out);
}